// Round 6
// baseline (334.908 us; speedup 1.0000x reference)
//
#include <hip/hip_runtime.h>
#include <cstdint>
#include <cstddef>

#define BATCH  8192
#define DIM    256
#define NSTRIP 16
#define SCOLS  512            // columns per strip (BATCH/NSTRIP)
#define MROWS  256            // rows per block (8 waves x 32 rows)
#define NTILE  64             // cols per inner iteration
#define NITER  (SCOLS/NTILE)  // 8
#define BCAP   96             // bucket capacity (expected 16/label)

static constexpr float INV_T   = 1.0f / 0.07f;
static constexpr float EXP2_SC = 1.4426950408889634f / 0.07f;  // log2(e)/T
static constexpr float MARGIN  = 0.2f;

typedef __attribute__((ext_vector_type(8))) short short8;
typedef __attribute__((ext_vector_type(4))) float f32x4;

__device__ __forceinline__ unsigned short f2bf(float f){
  unsigned int u = __float_as_uint(f);
  u += 0x7FFFu + ((u >> 16) & 1u);     // round-to-nearest-even
  return (unsigned short)(u >> 16);
}
__device__ __forceinline__ float bf2f(unsigned short h){
  return __uint_as_float((unsigned)h << 16);
}

// top-3 insert: max, med3, 2xmin, max (invariant t0>=t1>=t2)
__device__ __forceinline__ void ins3(float& t0, float& t1, float& t2, float s){
  float m0  = fmaxf(t0, s);
  float mid = __builtin_amdgcn_fmed3f(t0, t1, s);
  float lo  = fminf(fminf(t0, t1), s);
  t2 = fmaxf(t2, lo);
  t0 = m0; t1 = mid;
}

// ---- kernel 1: L2-normalize rows (fp32), cast to bf16; zero accum + bcnt
__global__ void norm_cast_kernel(const float* __restrict__ emb,
                                 unsigned short* __restrict__ E,
                                 float* __restrict__ accum,
                                 int* __restrict__ bcnt){
  if (blockIdx.x < 2) bcnt[blockIdx.x * 256 + threadIdx.x] = 0;
  if (blockIdx.x == 2 && threadIdx.x < 8) accum[threadIdx.x] = 0.0f;
  const int wave = threadIdx.x >> 6;
  const int lane = threadIdx.x & 63;
  const int row  = blockIdx.x * 4 + wave;
  const float4 v = *(const float4*)(emb + (size_t)row * DIM + lane * 4);
  float ss = v.x*v.x + v.y*v.y + v.z*v.z + v.w*v.w;
  #pragma unroll
  for (int m = 1; m < 64; m <<= 1) ss += __shfl_xor(ss, m, 64);
  float inv = 1.0f / fmaxf(sqrtf(ss), 1e-12f);
  ushort4 o;
  o.x = f2bf(v.x * inv); o.y = f2bf(v.y * inv);
  o.z = f2bf(v.z * inv); o.w = f2bf(v.w * inv);
  *(ushort4*)(E + (size_t)row * DIM + lane * 4) = o;
}

// ---- kernel 2: fused sim GEMM (bf16 MFMA) + online negatives statistics.
// Grid (NSTRIP, BATCH/MROWS) = (16,32) = 512 blocks; 512 thr = 8 waves; wave
// owns 32 rows. Exactly 2 blocks/CU in ONE resident round -> 16 waves/CU.
// launch_bounds(512,4): reg cap 128; lean live set ~112 fits (A 64 + stats 32
// + packed labels 4 + acc 8 + misc). Positives AND self handled in merge:
// all_s here includes every column (self too); top-3 masks same-label (which
// covers self). R1's proven single-buffer 2-barrier staging, bank-conflict-free.
// Strip-0 blocks also build the label buckets (consumed by merge, next dispatch).
__global__ __launch_bounds__(512, 4)
void sim_stats_kernel(const unsigned short* __restrict__ E,
                      const int* __restrict__ labels,
                      float* __restrict__ partials,
                      int* __restrict__ bcnt,
                      int* __restrict__ bucket){
  const int strip = blockIdx.x;
  const int rb    = blockIdx.y * MROWS;
  const int cs    = strip * SCOLS;
  const int tid   = threadIdx.x;
  const int wave  = tid >> 6;
  const int lane  = tid & 63;
  const int l     = lane & 15;   // column within 16-wide subtile / A-row
  const int q     = lane >> 4;   // quad: selects k-group and C row group

  // B staging: [chunk c=(kk*4+q)][col r 0..63] of 8 bf16 (16B each) = 32 KiB
  __shared__ short8 Bs[32 * 64];
  __shared__ int labs[SCOLS];    // 2 KiB

  labs[tid] = labels[cs + tid];

  // fold bucket building into strip-0 blocks (32 blocks x 256 rows)
  if (strip == 0 && tid < MROWS){
    const int r   = rb + tid;
    const int lab = labels[r];
    const int idx = atomicAdd(&bcnt[lab], 1);
    if (idx < BCAP) bucket[lab * BCAP + idx] = r;
  }

  const int row0 = rb + wave * 32;

  // A fragments for the wave's 32 rows, full K=256 (64 VGPR).
  short8 a[2][8];
  #pragma unroll
  for (int rt = 0; rt < 2; ++rt){
    const unsigned short* rp = E + (size_t)(row0 + rt*16 + l) * DIM + q * 8;
    #pragma unroll
    for (int kk = 0; kk < 8; ++kk)
      a[rt][kk] = *(const short8*)(rp + kk * 32);
  }

  // row labels packed 2x16-bit (labels < 512): slot s=rt*4+rr -> labp[s>>1]
  unsigned labp[4];
  #pragma unroll
  for (int k = 0; k < 4; ++k){
    const int s0 = 2 * k, s1 = 2 * k + 1;
    const unsigned lo = (unsigned)labels[row0 + (s0 >> 2) * 16 + q * 4 + (s0 & 3)];
    const unsigned hi = (unsigned)labels[row0 + (s1 >> 2) * 16 + q * 4 + (s1 & 3)];
    labp[k] = lo | (hi << 16);
  }

  float all_s[8], t0[8], t1[8], t2[8];
  #pragma unroll
  for (int s = 0; s < 8; ++s){
    all_s[s] = 0.f; t0[s] = -INFINITY; t1[s] = -INFINITY; t2[s] = -INFINITY;
  }

  #pragma unroll 1
  for (int it = 0; it < NITER; ++it){
    const int cb = cs + it * NTILE;
    __syncthreads();  // everyone done reading Bs
    // stage: wave handles chunks c = wave*4..+3; lane gathers column cb+lane
    #pragma unroll
    for (int ci = 0; ci < 4; ++ci){
      const int c = wave * 4 + ci;
      const unsigned short* g = E + (size_t)(cb + lane) * DIM + c * 8;
      __builtin_amdgcn_global_load_lds(
        (const __attribute__((address_space(1))) unsigned int*)g,
        (__attribute__((address_space(3))) unsigned int*)&Bs[c * 64],
        16, 0, 0);
    }
    __syncthreads();  // drains vmcnt: Bs ready

    #pragma unroll
    for (int t = 0; t < 4; ++t){
      const int labc = labs[it * NTILE + t * 16 + l];
      f32x4 acc0 = {0.f,0.f,0.f,0.f};
      f32x4 acc1 = {0.f,0.f,0.f,0.f};
      #pragma unroll
      for (int kk = 0; kk < 8; ++kk){
        short8 b = Bs[(kk * 4 + q) * 64 + t * 16 + l];
        acc0 = __builtin_amdgcn_mfma_f32_16x16x32_bf16(a[0][kk], b, acc0, 0, 0, 0);
        acc1 = __builtin_amdgcn_mfma_f32_16x16x32_bf16(a[1][kk], b, acc1, 0, 0, 0);
      }
      #pragma unroll
      for (int s = 0; s < 8; ++s){
        const float d  = (s < 4) ? acc0[s & 3] : acc1[s & 3];
        const float ex = __builtin_amdgcn_exp2f(d * EXP2_SC);
        all_s[s] += ex;
        const int ls = (s & 1) ? (int)(labp[s >> 1] >> 16)
                               : (int)(labp[s >> 1] & 0xffffu);
        const float sn = (ls == labc) ? -INFINITY : d;
        ins3(t0[s], t1[s], t2[s], sn);
      }
    }
  }

  // butterfly reduce over the 16 column-classes (disjoint-set merge: exact)
  #pragma unroll
  for (int mask = 1; mask < 16; mask <<= 1){
    #pragma unroll
    for (int s = 0; s < 8; ++s){
      all_s[s] += __shfl_xor(all_s[s], mask, 64);
      float b0 = __shfl_xor(t0[s], mask, 64);
      float b1 = __shfl_xor(t1[s], mask, 64);
      float b2 = __shfl_xor(t2[s], mask, 64);
      ins3(t0[s], t1[s], t2[s], b0);
      ins3(t0[s], t1[s], t2[s], b1);
      ins3(t0[s], t1[s], t2[s], b2);
    }
  }

  if (l == 0){
    #pragma unroll
    for (int s = 0; s < 8; ++s){
      const int grow = row0 + (s >> 2) * 16 + q * 4 + (s & 3);
      float* p = partials + (size_t)(strip * 4) * BATCH + grow;
      p[0]                 = all_s[s];
      p[(size_t)BATCH]     = t0[s];
      p[(size_t)2 * BATCH] = t1[s];
      p[(size_t)3 * BATCH] = t2[s];
    }
  }
}

// ---- kernel 3: per-row merge + exact positive stats + per-row losses.
// 2048 blocks x 256 thr = 4 waves, one wave per row.
__global__ void merge_kernel(const unsigned short* __restrict__ E,
                             const int* __restrict__ labels,
                             const int* __restrict__ bcnt,
                             const int* __restrict__ bucket,
                             const float* __restrict__ partials,
                             float* __restrict__ accum){
  const int wave = threadIdx.x >> 6;
  const int lane = threadIdx.x & 63;
  const int row  = blockIdx.x * 4 + wave;
  __shared__ float red[4][5];

  // positive-pair stats + self term over this row's label bucket (~17 entries)
  const int lab = labels[row];
  const int n   = min(bcnt[lab], BCAP);
  const ushort4 ev = *(const ushort4*)(E + (size_t)row * DIM + lane * 4);
  const float a0 = bf2f(ev.x), a1 = bf2f(ev.y), a2 = bf2f(ev.z), a3 = bf2f(ev.w);
  float ps = 0.f, pm = -INFINITY, selfex = 0.f;
  for (int j = 0; j < n; ++j){
    const int col = bucket[lab * BCAP + j];
    const ushort4 cv = *(const ushort4*)(E + (size_t)col * DIM + lane * 4);
    float d = a0 * bf2f(cv.x);
    d = fmaf(a1, bf2f(cv.y), d);
    d = fmaf(a2, bf2f(cv.z), d);
    d = fmaf(a3, bf2f(cv.w), d);
    #pragma unroll
    for (int m = 1; m < 64; m <<= 1) d += __shfl_xor(d, m, 64);
    const float e = __builtin_amdgcn_exp2f(d * EXP2_SC);
    if (col == row){            // wave-uniform branch
      selfex = e;
    } else {
      ps += e;
      pm  = fmaxf(pm, d);
    }
  }

  // merge the 16 strip partials (lane i holds strip i)
  float all_s = 0.f, t0 = -INFINITY, t1 = -INFINITY, t2 = -INFINITY;
  if (lane < NSTRIP){
    const float* p = partials + (size_t)(lane * 4) * BATCH + row;
    all_s = p[0];
    t0 = p[(size_t)BATCH]; t1 = p[(size_t)2 * BATCH]; t2 = p[(size_t)3 * BATCH];
  }
  #pragma unroll
  for (int mask = 1; mask < 16; mask <<= 1){
    all_s += __shfl_xor(all_s, mask, 64);
    float b0 = __shfl_xor(t0, mask, 64);
    float b1 = __shfl_xor(t1, mask, 64);
    float b2 = __shfl_xor(t2, mask, 64);
    ins3(t0, t1, t2, b0); ins3(t0, t1, t2, b1); ins3(t0, t1, t2, b2);
  }

  if (lane == 0){
    all_s -= selfex;            // hot loop included self; remove it
    const float pos_m = pm * INV_T;
    const float u0 = t0 * INV_T, u1 = t1 * INV_T, u2 = t2 * INV_T;
    const bool has_pos = pm > -INFINITY;
    float vb = 0.f, vh = 0.f, vhp = 0.f, vm = 0.f, vv = 0.f;
    if (has_pos){
      vhp = 1.f;
      vb  = -logf(ps / (all_s + 1e-10f) + 1e-10f);
      const float hnm = (u0 + u1 + u2) * (1.f/3.f);
      vh  = fmaxf(hnm - pos_m + MARGIN, 0.f);
      if (u0 > -INFINITY){
        vv = 1.f;
        vm = fmaxf(u0 - pos_m + MARGIN, 0.f);
      }
    }
    red[wave][0] = vb; red[wave][1] = vh; red[wave][2] = vhp;
    red[wave][3] = vm; red[wave][4] = vv;
  }
  __syncthreads();
  if (threadIdx.x < 5){
    float s = red[0][threadIdx.x] + red[1][threadIdx.x]
            + red[2][threadIdx.x] + red[3][threadIdx.x];
    atomicAdd(&accum[threadIdx.x], s);
  }
}

// ---- kernel 4: final scalar combine
__global__ void final_kernel(const float* __restrict__ accum,
                             float* __restrict__ out){
  if (threadIdx.x == 0){
    const float nhp   = fmaxf(accum[2], 1.f);
    const float basic = accum[0] / nhp;
    const float hard  = accum[1] / nhp;
    const float marg  = (accum[4] > 0.f) ? (accum[3] / fmaxf(accum[4], 1.f)) : 0.f;
    out[0] = basic + 0.5f * hard + 0.1f * marg;
  }
}

extern "C" void kernel_launch(void* const* d_in, const int* in_sizes, int n_in,
                              void* d_out, int out_size, void* d_ws, size_t ws_size,
                              hipStream_t stream){
  const float* emb  = (const float*)d_in[0];
  const int* labels = (const int*)d_in[1];
  float* out        = (float*)d_out;
  char* ws          = (char*)d_ws;

  size_t off = 0;
  unsigned short* E = (unsigned short*)(ws + off); off += (size_t)BATCH * DIM * 2;        // 4 MiB
  float* partials   = (float*)(ws + off);          off += (size_t)NSTRIP * 4 * BATCH * 4; // 2 MiB
  int*   bcnt       = (int*)(ws + off);            off += 512 * 4;
  int*   bucket     = (int*)(ws + off);            off += (size_t)512 * BCAP * 4;
  float* accum      = (float*)(ws + off);          off += 8 * 4;

  norm_cast_kernel<<<BATCH/4, 256, 0, stream>>>(emb, E, accum, bcnt);
  sim_stats_kernel<<<dim3(NSTRIP, BATCH/MROWS), 512, 0, stream>>>(E, labels, partials, bcnt, bucket);
  merge_kernel<<<BATCH/4, 256, 0, stream>>>(E, labels, bcnt, bucket, partials, accum);
  final_kernel<<<1, 64, 0, stream>>>(accum, out);
}